// Round 7
// baseline (164.402 us; speedup 1.0000x reference)
//
#include <hip/hip_runtime.h>
#include <hip/hip_fp16.h>
#include <hip/hip_cooperative_groups.h>

namespace cg = cooperative_groups;

// Capsule dynamic routing. fp32 accumulate, f16 W/x via v_dot2_f32_f16.
// x:[B,I,K]=32x2048x8, W:[J,I,D,K]=32x2048x16x8, out v:[B,J,D]=32x32x16.
// b-logits linear in v -> keep only vsum[b,j,d]; passes recompute u_hat.
// R7: R6's coop launch was silently REJECTED (absmax == max|ref| == empty-
// stub signature => out never written; 2 blk/CU occupancy validation).
// Now: 256 blocks (1/CU), 512 thr, launch_bounds(512,2), ~2.3KB LDS only.
// Pass 1 fuses the W transpose: reads W f32 once (the unavoidable 33.5MB),
// computes u in fp32, writes Wt f16 + xh f16; passes 2-3 read the block's
// OWN 64KB Wt slice (guaranteed same-XCD L2 hit) via fdot2. Occupancy query
// + coop return code checked, with an equivalent multi-kernel fallback.

#define ICAP    2048
#define JD      512          // JCAP*DDIM
#define S_ELEMS 16384        // BATCH*JCAP*DDIM
#define EPSQ    1e-7f
#define NBLK    256          // 1 block per CU
#define ICH     8            // i's per block

typedef _Float16 h2v __attribute__((ext_vector_type(2)));
union H8 { int4 i4; h2v h[4]; };

#if defined(__has_builtin) && __has_builtin(__builtin_amdgcn_fdot2)
#define FDOT2(a, b, c) __builtin_amdgcn_fdot2((a), (b), (c), false)
#else
__device__ inline float FDOT2(h2v a, h2v b, float c) {
    return c + (float)a[0] * (float)b[0] + (float)a[1] * (float)b[1];
}
#endif
#if defined(__has_builtin) && __has_builtin(__builtin_amdgcn_rcpf)
#define FAST_RCP(x) __builtin_amdgcn_rcpf(x)
#else
#define FAST_RCP(x) (1.0f / (x))
#endif
#if defined(__has_builtin) && __has_builtin(__builtin_amdgcn_rsqf)
#define FAST_RSQ(x) __builtin_amdgcn_rsqf(x)
#else
#define FAST_RSQ(x) rsqrtf(x)
#endif

// ---------------------------------------------------------------------------
// Epilogue shared by both pass phases: fp16 partial slice, disjoint per block.
// ---------------------------------------------------------------------------
__device__ inline void write_partials(int bl, int wave, int j, int dh,
                                      const float sacc[4][8],
                                      __half* __restrict__ partials) {
    __half* pout = partials + (size_t)bl * S_ELEMS;
#pragma unroll
    for (int bb = 0; bb < 4; ++bb) {
        const int b = wave + 8 * bb;
        union { int4 v; __half2 h[4]; } pk;
#pragma unroll
        for (int r = 0; r < 4; ++r)
            pk.h[r] = __floats2half2_rn(sacc[bb][2 * r], sacc[bb][2 * r + 1]);
        *reinterpret_cast<int4*>(pout + b * JD + j * 16 + dh * 8) = pk.v;
    }
}

// ---------------------------------------------------------------------------
// Phase 1: pass with c = 1/32 (softmax of zeros) fused with W f32->f16
// transpose (Wt slot = i*512 + cc*64 + m, m = 2j+dh, halves
// W[j,i,dh*64+8cc..+7]) and x f32->f16 conversion.
// ---------------------------------------------------------------------------
__device__ void phase_first(int bl, int tid,
                            const float4* __restrict__ Wv,
                            const float* __restrict__ x,
                            int4* __restrict__ Wt, __half* __restrict__ xh,
                            __half* __restrict__ partials) {
    const int wave = tid >> 6, lane = tid & 63;
    const int j = lane & 31, dh = lane >> 5, m = 2 * j + dh;
    const int i0 = bl * ICH;

    // x slice f32 -> f16 (block owns i0..i0+7: 32b x 64 floats each)
#pragma unroll
    for (int q = 0; q < 4; ++q) {
        const int idx = q * 512 + tid;
        const int b = idx >> 6, r = idx & 63;
        const size_t xi = (size_t)b * (ICAP * 8) + (size_t)i0 * 8 + r;
        xh[xi] = __float2half(x[xi]);
    }

    float sacc[4][8];
#pragma unroll
    for (int bb = 0; bb < 4; ++bb)
#pragma unroll
        for (int r = 0; r < 8; ++r) sacc[bb][r] = 0.f;

#pragma unroll 2
    for (int il = 0; il < ICH; ++il) {
        const int gi = i0 + il;
        // lane's 64 W floats, f32, from original layout (line-complete reads)
        float4 wf[16];
        const float4* wp = Wv + (size_t)j * 65536 + (size_t)gi * 32 + dh * 16;
#pragma unroll
        for (int cc = 0; cc < 16; ++cc) wf[cc] = wp[cc];

        // emit Wt f16 (coalesced across m for each cc)
        int4* wt = Wt + (size_t)gi * 512 + m;
#pragma unroll
        for (int cc = 0; cc < 8; ++cc) {
            const float4 a = wf[2 * cc], b = wf[2 * cc + 1];
            H8 h;
            h.h[0] = h2v{(_Float16)a.x, (_Float16)a.y};
            h.h[1] = h2v{(_Float16)a.z, (_Float16)a.w};
            h.h[2] = h2v{(_Float16)b.x, (_Float16)b.y};
            h.h[3] = h2v{(_Float16)b.z, (_Float16)b.w};
            wt[cc * 64] = h.i4;
        }

        // pass-1 accumulation, c = 1/32 exactly
#pragma unroll
        for (int bb = 0; bb < 4; ++bb) {
            const int b = wave + 8 * bb;
            const float* xp = x + ((size_t)b * ICAP + gi) * 8;
            const float4 x0 = *reinterpret_cast<const float4*>(xp);
            const float4 x1 = *reinterpret_cast<const float4*>(xp + 4);
#pragma unroll
            for (int r = 0; r < 8; ++r) {
                const float4 wa = wf[2 * r], wb = wf[2 * r + 1];
                float acc;
                acc = wa.x * x0.x;
                acc = fmaf(wa.y, x0.y, acc);
                acc = fmaf(wa.z, x0.z, acc);
                acc = fmaf(wa.w, x0.w, acc);
                acc = fmaf(wb.x, x1.x, acc);
                acc = fmaf(wb.y, x1.y, acc);
                acc = fmaf(wb.z, x1.z, acc);
                acc = fmaf(wb.w, x1.w, acc);
                sacc[bb][r] = fmaf(0.03125f, acc, sacc[bb][r]);
            }
        }
    }
    write_partials(bl, wave, j, dh, sacc, partials);
}

// ---------------------------------------------------------------------------
// Phase 2/3: routing pass from Wt f16 (block's own slice, L2-hot) + xh,
// u via fdot2, softmax over j in-wave (no max subtraction: |t| <~ 3).
// ---------------------------------------------------------------------------
__device__ void phase_pass(int bl, int tid,
                           const int4* __restrict__ Wt,
                           const int4* __restrict__ xh,
                           const float* __restrict__ vsum,
                           __half* __restrict__ partials) {
    const int wave = tid >> 6, lane = tid & 63;
    const int j = lane & 31, dh = lane >> 5, m = 2 * j + dh;
    const int i0 = bl * ICH;

    float vs[4][8], sacc[4][8];
#pragma unroll
    for (int bb = 0; bb < 4; ++bb) {
        const int b = wave + 8 * bb;
        const float* vp = vsum + b * JD + j * 16 + dh * 8;
        const float4 a  = *reinterpret_cast<const float4*>(vp);
        const float4 bq = *reinterpret_cast<const float4*>(vp + 4);
        vs[bb][0]=a.x; vs[bb][1]=a.y; vs[bb][2]=a.z; vs[bb][3]=a.w;
        vs[bb][4]=bq.x; vs[bb][5]=bq.y; vs[bb][6]=bq.z; vs[bb][7]=bq.w;
#pragma unroll
        for (int r = 0; r < 8; ++r) sacc[bb][r] = 0.f;
    }

    const int4* wp = Wt + (size_t)i0 * 512 + m;

#pragma unroll 2
    for (int il = 0; il < ICH; ++il) {
        H8 w8[8];
#pragma unroll
        for (int cc = 0; cc < 8; ++cc)
            w8[cc].i4 = wp[(size_t)il * 512 + cc * 64];

        const int gi = i0 + il;
#pragma unroll
        for (int bb = 0; bb < 4; ++bb) {
            const int b = wave + 8 * bb;
            H8 xv;
            xv.i4 = xh[(size_t)b * ICAP + gi];

            float u[8], tpart = 0.f;
#pragma unroll
            for (int r = 0; r < 8; ++r) {
                float acc = FDOT2(w8[r].h[0], xv.h[0], 0.f);
                acc = FDOT2(w8[r].h[1], xv.h[1], acc);
                acc = FDOT2(w8[r].h[2], xv.h[2], acc);
                acc = FDOT2(w8[r].h[3], xv.h[3], acc);
                u[r] = acc;
                tpart = fmaf(acc, vs[bb][r], tpart);
            }
            const float t = tpart + __shfl_xor(tpart, 32);
            const float e = __expf(t);
            float se = e;
#pragma unroll
            for (int off = 1; off <= 16; off <<= 1)
                se += __shfl_xor(se, off);
            const float c = e * FAST_RCP(se);
#pragma unroll
            for (int r = 0; r < 8; ++r)
                sacc[bb][r] = fmaf(c, u[r], sacc[bb][r]);
        }
    }
    write_partials(bl, wave, j, dh, sacc, partials);
}

// ---------------------------------------------------------------------------
// Reduce 256 fp16 slices for this block's 64 elements + squash.
// ridx: 0 -> vsum = v, 1 -> vsum += v, 2 -> out = v.
// ---------------------------------------------------------------------------
__device__ void phase_reduce(int bl, int tid,
                             const __half* __restrict__ partials,
                             float* __restrict__ vsum,
                             float* __restrict__ out, int ridx) {
    __shared__ float rbuf[8][72];
    const int eL = tid & 63, sg = tid >> 6;
    const int e = bl * 64 + eL;
    float s = 0.f;
    const __half* p = partials + (size_t)sg * S_ELEMS + e;
#pragma unroll
    for (int n = 0; n < 32; ++n)
        s += __half2float(p[(size_t)n * 8 * S_ELEMS]);
    rbuf[sg][eL] = s;
    __syncthreads();
    if (tid < 64) {
        s = 0.f;
#pragma unroll
        for (int k = 0; k < 8; ++k) s += rbuf[k][tid];
        float n2 = s * s;
#pragma unroll
        for (int off = 1; off <= 8; off <<= 1)
            n2 += __shfl_xor(n2, off);               // sum over d=16
        const float scale = n2 * FAST_RCP(1.f + n2) * FAST_RSQ(n2 + EPSQ);
        const float v = s * scale;
        const int eo = bl * 64 + tid;
        if (ridx == 0)      vsum[eo] = v;            // vsum poisoned pre-r0
        else if (ridx == 1) vsum[eo] += v;
        else                out[eo] = v;
    }
    __syncthreads();
}

// ---------------------------------------------------------------------------
// Single cooperative kernel (preferred path).
// ---------------------------------------------------------------------------
__global__ __launch_bounds__(512, 2)
void caps_coop(const float4* __restrict__ Wv, const float* __restrict__ x,
               int4* __restrict__ Wt, __half* __restrict__ xh,
               __half* __restrict__ partials, float* __restrict__ vsum,
               float* __restrict__ out) {
    cg::grid_group grid = cg::this_grid();
    const int bl = blockIdx.x, tid = threadIdx.x;
    phase_first(bl, tid, Wv, x, Wt, xh, partials);
    grid.sync();
    phase_reduce(bl, tid, partials, vsum, out, 0);
    grid.sync();
    phase_pass(bl, tid, Wt, (const int4*)xh, vsum, partials);
    grid.sync();
    phase_reduce(bl, tid, partials, vsum, out, 1);
    grid.sync();
    phase_pass(bl, tid, Wt, (const int4*)xh, vsum, partials);
    grid.sync();
    phase_reduce(bl, tid, partials, vsum, out, 2);
}

// Fallback: same phases as separate kernels (kernel boundary = grid sync).
__global__ __launch_bounds__(512, 2)
void k_first(const float4* Wv, const float* x, int4* Wt, __half* xh,
             __half* partials) {
    phase_first(blockIdx.x, threadIdx.x, Wv, x, Wt, xh, partials);
}
__global__ __launch_bounds__(512, 2)
void k_pass(const int4* Wt, const int4* xh, const float* vsum,
            __half* partials) {
    phase_pass(blockIdx.x, threadIdx.x, Wt, xh, vsum, partials);
}
__global__ __launch_bounds__(512, 2)
void k_reduce(const __half* partials, float* vsum, float* out, int ridx) {
    phase_reduce(blockIdx.x, threadIdx.x, partials, vsum, out, ridx);
}

extern "C" void kernel_launch(void* const* d_in, const int* in_sizes, int n_in,
                              void* d_out, int out_size, void* d_ws, size_t ws_size,
                              hipStream_t stream) {
    const float*  x  = (const float*)d_in[0];   // [32,2048,8]
    const float4* Wv = (const float4*)d_in[1];  // [32,2048,16,8]
    float* out = (float*)d_out;                 // [32,32,16]

    // ws: Wt f16 16.78 MB | xh 1 MB | partials 8 MB | vsum 64 KB
    int4*   Wt       = (int4*)d_ws;
    __half* xh       = (__half*)((char*)d_ws + (size_t)ICAP * 512 * 16);
    __half* partials = (__half*)((char*)xh + (size_t)32 * ICAP * 8 * 2);
    float*  vsum     = (float*)((char*)partials +
                                (size_t)NBLK * S_ELEMS * sizeof(__half));

    int occ = 0;
    bool coop = (hipSuccess == hipOccupancyMaxActiveBlocksPerMultiprocessor(
                     &occ, reinterpret_cast<const void*>(&caps_coop), 512, 0))
                && occ >= 1;
    if (coop) {
        void* args[] = { (void*)&Wv, (void*)&x, (void*)&Wt, (void*)&xh,
                         (void*)&partials, (void*)&vsum, (void*)&out };
        coop = (hipSuccess == hipLaunchCooperativeKernel(
                    (void*)caps_coop, dim3(NBLK), dim3(512), args, 0, stream));
    }
    if (!coop) {
        k_first<<<NBLK, 512, 0, stream>>>(Wv, x, Wt, xh, partials);
        k_reduce<<<NBLK, 512, 0, stream>>>(partials, vsum, out, 0);
        k_pass<<<NBLK, 512, 0, stream>>>(Wt, (const int4*)xh, vsum, partials);
        k_reduce<<<NBLK, 512, 0, stream>>>(partials, vsum, out, 1);
        k_pass<<<NBLK, 512, 0, stream>>>(Wt, (const int4*)xh, vsum, partials);
        k_reduce<<<NBLK, 512, 0, stream>>>(partials, vsum, out, 2);
    }
}

// Round 8
// 164.011 us; speedup vs baseline: 1.0024x; 1.0024x over previous
//
#include <hip/hip_runtime.h>
#include <hip/hip_fp16.h>

// Capsule dynamic routing. fp32 accumulate, f16 W/x via v_dot2_f32_f16.
// x:[B,I,K]=32x2048x8, W:[J,I,D,K]=32x2048x16x8, out v:[B,J,D]=32x32x16.
// b-logits linear in v -> keep only vsum[b,j,d]; passes recompute u_hat.
// R8: R7's cooperative path measured 249us/dispatch with only ~30us of
// phase work -> grid.sync() costs ~40us each on 8 XCDs (device-scope
// barrier + cross-XCD coherence). Graph-captured kernel boundaries are the
// CHEAP grid barrier (~2-5us). So: 6 plain dispatches, coop deleted.
// Pass 1 fuses the W transpose: reads W f32 once (the unavoidable 33.5MB),
// computes u in fp32, writes Wt f16 + xh f16; passes 2-3 read the block's
// OWN 64KB Wt slice (same-XCD L2 hit) via fdot2. Reduce phases sum 256
// fp16 partial slices and squash in-wave.

#define ICAP    2048
#define JD      512          // JCAP*DDIM
#define S_ELEMS 16384        // BATCH*JCAP*DDIM
#define EPSQ    1e-7f
#define NBLK    256          // 1 block per CU
#define ICH     8            // i's per block

typedef _Float16 h2v __attribute__((ext_vector_type(2)));
union H8 { int4 i4; h2v h[4]; };

#if defined(__has_builtin) && __has_builtin(__builtin_amdgcn_fdot2)
#define FDOT2(a, b, c) __builtin_amdgcn_fdot2((a), (b), (c), false)
#else
__device__ inline float FDOT2(h2v a, h2v b, float c) {
    return c + (float)a[0] * (float)b[0] + (float)a[1] * (float)b[1];
}
#endif
#if defined(__has_builtin) && __has_builtin(__builtin_amdgcn_rcpf)
#define FAST_RCP(x) __builtin_amdgcn_rcpf(x)
#else
#define FAST_RCP(x) (1.0f / (x))
#endif
#if defined(__has_builtin) && __has_builtin(__builtin_amdgcn_rsqf)
#define FAST_RSQ(x) __builtin_amdgcn_rsqf(x)
#else
#define FAST_RSQ(x) rsqrtf(x)
#endif

// ---------------------------------------------------------------------------
// Epilogue shared by both pass kernels: fp16 partial slice, disjoint/block.
// ---------------------------------------------------------------------------
__device__ inline void write_partials(int bl, int wave, int j, int dh,
                                      const float sacc[4][8],
                                      __half* __restrict__ partials) {
    __half* pout = partials + (size_t)bl * S_ELEMS;
#pragma unroll
    for (int bb = 0; bb < 4; ++bb) {
        const int b = wave + 8 * bb;
        union { int4 v; __half2 h[4]; } pk;
#pragma unroll
        for (int r = 0; r < 4; ++r)
            pk.h[r] = __floats2half2_rn(sacc[bb][2 * r], sacc[bb][2 * r + 1]);
        *reinterpret_cast<int4*>(pout + b * JD + j * 16 + dh * 8) = pk.v;
    }
}

// ---------------------------------------------------------------------------
// Kernel 1: pass with c = 1/32 (softmax of zeros) fused with W f32->f16
// transpose (Wt slot = i*512 + cc*64 + m, m = 2j+dh, halves
// W[j,i,dh*64+8cc..+7]) and x f32->f16 conversion.
// ---------------------------------------------------------------------------
__global__ __launch_bounds__(512, 2)
void k_first(const float4* __restrict__ Wv, const float* __restrict__ x,
             int4* __restrict__ Wt, __half* __restrict__ xh,
             __half* __restrict__ partials) {
    const int bl = blockIdx.x, tid = threadIdx.x;
    const int wave = tid >> 6, lane = tid & 63;
    const int j = lane & 31, dh = lane >> 5, m = 2 * j + dh;
    const int i0 = bl * ICH;

    // x slice f32 -> f16 (block owns i0..i0+7: 32b x 64 floats each)
#pragma unroll
    for (int q = 0; q < 4; ++q) {
        const int idx = q * 512 + tid;
        const int b = idx >> 6, r = idx & 63;
        const size_t xi = (size_t)b * (ICAP * 8) + (size_t)i0 * 8 + r;
        xh[xi] = __float2half(x[xi]);
    }

    float sacc[4][8];
#pragma unroll
    for (int bb = 0; bb < 4; ++bb)
#pragma unroll
        for (int r = 0; r < 8; ++r) sacc[bb][r] = 0.f;

#pragma unroll 2
    for (int il = 0; il < ICH; ++il) {
        const int gi = i0 + il;
        // lane's 64 W floats, f32, original layout (line-complete reads)
        float4 wf[16];
        const float4* wp = Wv + (size_t)j * 65536 + (size_t)gi * 32 + dh * 16;
#pragma unroll
        for (int cc = 0; cc < 16; ++cc) wf[cc] = wp[cc];

        // emit Wt f16 (coalesced across m for each cc)
        int4* wt = Wt + (size_t)gi * 512 + m;
#pragma unroll
        for (int cc = 0; cc < 8; ++cc) {
            const float4 a = wf[2 * cc], b = wf[2 * cc + 1];
            H8 h;
            h.h[0] = h2v{(_Float16)a.x, (_Float16)a.y};
            h.h[1] = h2v{(_Float16)a.z, (_Float16)a.w};
            h.h[2] = h2v{(_Float16)b.x, (_Float16)b.y};
            h.h[3] = h2v{(_Float16)b.z, (_Float16)b.w};
            wt[cc * 64] = h.i4;
        }

        // pass-1 accumulation, c = 1/32 exactly
#pragma unroll
        for (int bb = 0; bb < 4; ++bb) {
            const int b = wave + 8 * bb;
            const float* xp = x + ((size_t)b * ICAP + gi) * 8;
            const float4 x0 = *reinterpret_cast<const float4*>(xp);
            const float4 x1 = *reinterpret_cast<const float4*>(xp + 4);
#pragma unroll
            for (int r = 0; r < 8; ++r) {
                const float4 wa = wf[2 * r], wb = wf[2 * r + 1];
                float acc;
                acc = wa.x * x0.x;
                acc = fmaf(wa.y, x0.y, acc);
                acc = fmaf(wa.z, x0.z, acc);
                acc = fmaf(wa.w, x0.w, acc);
                acc = fmaf(wb.x, x1.x, acc);
                acc = fmaf(wb.y, x1.y, acc);
                acc = fmaf(wb.z, x1.z, acc);
                acc = fmaf(wb.w, x1.w, acc);
                sacc[bb][r] = fmaf(0.03125f, acc, sacc[bb][r]);
            }
        }
    }
    write_partials(bl, wave, j, dh, sacc, partials);
}

// ---------------------------------------------------------------------------
// Kernels 3/5: routing pass from Wt f16 (block's own slice, L2-hot) + xh,
// u via fdot2, softmax over j in-wave (no max subtraction: |t| <~ 3).
// ---------------------------------------------------------------------------
__global__ __launch_bounds__(512, 2)
void k_pass(const int4* __restrict__ Wt, const int4* __restrict__ xh,
            const float* __restrict__ vsum, __half* __restrict__ partials) {
    const int bl = blockIdx.x, tid = threadIdx.x;
    const int wave = tid >> 6, lane = tid & 63;
    const int j = lane & 31, dh = lane >> 5, m = 2 * j + dh;
    const int i0 = bl * ICH;

    float vs[4][8], sacc[4][8];
#pragma unroll
    for (int bb = 0; bb < 4; ++bb) {
        const int b = wave + 8 * bb;
        const float* vp = vsum + b * JD + j * 16 + dh * 8;
        const float4 a  = *reinterpret_cast<const float4*>(vp);
        const float4 bq = *reinterpret_cast<const float4*>(vp + 4);
        vs[bb][0]=a.x; vs[bb][1]=a.y; vs[bb][2]=a.z; vs[bb][3]=a.w;
        vs[bb][4]=bq.x; vs[bb][5]=bq.y; vs[bb][6]=bq.z; vs[bb][7]=bq.w;
#pragma unroll
        for (int r = 0; r < 8; ++r) sacc[bb][r] = 0.f;
    }

    const int4* wp = Wt + (size_t)i0 * 512 + m;

#pragma unroll 2
    for (int il = 0; il < ICH; ++il) {
        H8 w8[8];
#pragma unroll
        for (int cc = 0; cc < 8; ++cc)
            w8[cc].i4 = wp[(size_t)il * 512 + cc * 64];

        const int gi = i0 + il;
#pragma unroll
        for (int bb = 0; bb < 4; ++bb) {
            const int b = wave + 8 * bb;
            H8 xv;
            xv.i4 = xh[(size_t)b * ICAP + gi];

            float u[8], tpart = 0.f;
#pragma unroll
            for (int r = 0; r < 8; ++r) {
                float acc = FDOT2(w8[r].h[0], xv.h[0], 0.f);
                acc = FDOT2(w8[r].h[1], xv.h[1], acc);
                acc = FDOT2(w8[r].h[2], xv.h[2], acc);
                acc = FDOT2(w8[r].h[3], xv.h[3], acc);
                u[r] = acc;
                tpart = fmaf(acc, vs[bb][r], tpart);
            }
            const float t = tpart + __shfl_xor(tpart, 32);
            const float e = __expf(t);
            float se = e;
#pragma unroll
            for (int off = 1; off <= 16; off <<= 1)
                se += __shfl_xor(se, off);
            const float c = e * FAST_RCP(se);
#pragma unroll
            for (int r = 0; r < 8; ++r)
                sacc[bb][r] = fmaf(c, u[r], sacc[bb][r]);
        }
    }
    write_partials(bl, wave, j, dh, sacc, partials);
}

// ---------------------------------------------------------------------------
// Kernels 2/4/6: reduce 256 fp16 slices for this block's 64 elements +
// squash. ridx: 0 -> vsum = v, 1 -> vsum += v, 2 -> out = v.
// ---------------------------------------------------------------------------
__global__ __launch_bounds__(512, 2)
void k_reduce(const __half* __restrict__ partials, float* __restrict__ vsum,
              float* __restrict__ out, int ridx) {
    __shared__ float rbuf[8][72];
    const int bl = blockIdx.x, tid = threadIdx.x;
    const int eL = tid & 63, sg = tid >> 6;
    const int e = bl * 64 + eL;
    float s = 0.f;
    const __half* p = partials + (size_t)sg * S_ELEMS + e;
#pragma unroll
    for (int n = 0; n < 32; ++n)
        s += __half2float(p[(size_t)n * 8 * S_ELEMS]);
    rbuf[sg][eL] = s;
    __syncthreads();
    if (tid < 64) {
        s = 0.f;
#pragma unroll
        for (int k = 0; k < 8; ++k) s += rbuf[k][tid];
        float n2 = s * s;
#pragma unroll
        for (int off = 1; off <= 8; off <<= 1)
            n2 += __shfl_xor(n2, off);               // sum over d=16
        const float scale = n2 * FAST_RCP(1.f + n2) * FAST_RSQ(n2 + EPSQ);
        const float v = s * scale;
        const int eo = bl * 64 + tid;
        if (ridx == 0)      vsum[eo] = v;            // vsum poisoned pre-r0
        else if (ridx == 1) vsum[eo] += v;
        else                out[eo] = v;
    }
}

extern "C" void kernel_launch(void* const* d_in, const int* in_sizes, int n_in,
                              void* d_out, int out_size, void* d_ws, size_t ws_size,
                              hipStream_t stream) {
    const float*  x  = (const float*)d_in[0];   // [32,2048,8]
    const float4* Wv = (const float4*)d_in[1];  // [32,2048,16,8]
    float* out = (float*)d_out;                 // [32,32,16]

    // ws: Wt f16 16.78 MB | xh 1 MB | partials 8 MB | vsum 64 KB
    int4*   Wt       = (int4*)d_ws;
    __half* xh       = (__half*)((char*)d_ws + (size_t)ICAP * 512 * 16);
    __half* partials = (__half*)((char*)xh + (size_t)32 * ICAP * 8 * 2);
    float*  vsum     = (float*)((char*)partials +
                                (size_t)NBLK * S_ELEMS * sizeof(__half));

    k_first<<<NBLK, 512, 0, stream>>>(Wv, x, Wt, xh, partials);
    k_reduce<<<NBLK, 512, 0, stream>>>(partials, vsum, out, 0);
    k_pass<<<NBLK, 512, 0, stream>>>(Wt, (const int4*)xh, vsum, partials);
    k_reduce<<<NBLK, 512, 0, stream>>>(partials, vsum, out, 1);
    k_pass<<<NBLK, 512, 0, stream>>>(Wt, (const int4*)xh, vsum, partials);
    k_reduce<<<NBLK, 512, 0, stream>>>(partials, vsum, out, 2);
}